// Round 1
// baseline (109.279 us; speedup 1.0000x reference)
//
#include <hip/hip_runtime.h>

constexpr int BLOCK = 256;
constexpr int IPT = 4;  // anchors per thread

__global__ __launch_bounds__(BLOCK) void assign_cls_label_kernel(
    const float* __restrict__ anchorss,   // (B,N,4) y,x,h,w  (or y1,x1,y2,x2 if !use_anchor)
    const float* __restrict__ gt_bboxess, // (B,A,4) y1,x1,y2,x2
    const int* __restrict__ gt_counts,    // (B,1)
    const int* __restrict__ use_anchor_p, // scalar
    int* __restrict__ out,                // (B,N)
    int N, int A)
{
#pragma clang fp contract(off)
    extern __shared__ float smem[];
    float4* s_box = reinterpret_cast<float4*>(smem); // (gy1,gx1,gy2,gx2)
    float*  s_ga  = smem + 4 * A;                    // gt areas
    __shared__ int s_count;

    const int b   = blockIdx.y;
    const int tid = threadIdx.x;

    // Stage gt boxes + areas into LDS (exact op order as reference: two subs, one mul)
    for (int i = tid; i < A; i += BLOCK) {
        float4 g = reinterpret_cast<const float4*>(gt_bboxess)[(size_t)b * A + i];
        s_box[i] = g;
        s_ga[i]  = (g.z - g.x) * (g.w - g.y);  // (gy2-gy1)*(gx2-gx1)
    }
    if (tid == 0) s_count = gt_counts[b];
    __syncthreads();

    const int count      = s_count;
    const int use_anchor = use_anchor_p[0];

    const int n0 = (blockIdx.x * BLOCK + tid) * IPT;
    if (n0 >= N) return;
    const int nk = min(IPT, N - n0);

    float y1[IPT], x1[IPT], y2[IPT], x2[IPT], area[IPT];
    const float4* arow = reinterpret_cast<const float4*>(anchorss) + (size_t)b * N;
    for (int k = 0; k < IPT; ++k) {
        const int n = (k < nk) ? (n0 + k) : (N - 1);   // clamp for tail (results discarded)
        float4 a = arow[n];
        if (use_anchor) {
            const float h = a.z, w = a.w;
            y1[k]   = a.x - h * 0.5f;   // y - h/2 (h/2 exact; sub rounds once, same as ref)
            y2[k]   = y1[k] + h;
            x1[k]   = a.y - w * 0.5f;
            x2[k]   = x1[k] + w;
            area[k] = h * w;
        } else {
            y1[k] = a.x; x1[k] = a.y; y2[k] = a.z; x2[k] = a.w;
            area[k] = (y2[k] - y1[k]) * (x2[k] - x1[k]);
        }
    }

    int pos[IPT] = {0, 0, 0, 0};
    for (int gi = 0; gi < count; ++gi) {
        const float4 g  = s_box[gi];
        const float  ga = s_ga[gi];
#pragma unroll
        for (int k = 0; k < IPT; ++k) {
            // clip(x, lo, hi) == med3(x, lo, hi) for lo<=hi, NaN-free: exact selection
            const float yy1 = __builtin_amdgcn_fmed3f(y1[k], g.x, g.z);
            const float yy2 = __builtin_amdgcn_fmed3f(y2[k], g.x, g.z);
            const float xx1 = __builtin_amdgcn_fmed3f(x1[k], g.y, g.w);
            const float xx2 = __builtin_amdgcn_fmed3f(x2[k], g.y, g.w);
            const float inter = (yy2 - yy1) * (xx2 - xx1);
            const float u     = (area[k] + ga) - inter;   // same assoc as ref
            const float hu    = 0.5f * u;                  // exact scaling
            // inter >= u/2  ==>  fl(inter/u) >= 0.5 always (monotone rounding, u>0)
            pos[k] |= (inter >= hu);
            // fl(inter/u) can round UP to 0.5 only for inter in [hu*(1-2^-23), hu):
            // rare -> exact IEEE fp32 division fallback (execz-skipped almost always)
            if (__builtin_expect((inter < hu) & (inter >= hu * 0.99999988f), 0)) {
                pos[k] |= ((inter / u) >= 0.5f);
            }
        }
    }

    const size_t ob = (size_t)b * N + n0;
    if (nk == IPT) {
        *reinterpret_cast<int4*>(out + ob) = make_int4(pos[0], pos[1], pos[2], pos[3]);
    } else {
        for (int k = 0; k < nk; ++k) out[ob + k] = pos[k];
    }
}

extern "C" void kernel_launch(void* const* d_in, const int* in_sizes, int n_in,
                              void* d_out, int out_size, void* d_ws, size_t ws_size,
                              hipStream_t stream) {
    const float* anchorss   = (const float*)d_in[0];
    const float* gt_bboxess = (const float*)d_in[1];
    const int*   gt_counts  = (const int*)d_in[2];
    const int*   use_anchor = (const int*)d_in[3];
    int*         out        = (int*)d_out;

    const int B = in_sizes[2];              // gt_counts is (B,1)
    const int A = in_sizes[1] / (4 * B);    // gt_bboxess is (B,A,4)
    const int N = in_sizes[0] / (4 * B);    // anchorss   is (B,N,4)

    dim3 grid((N + BLOCK * IPT - 1) / (BLOCK * IPT), B);
    size_t smem = (size_t)(5 * A) * sizeof(float);
    hipLaunchKernelGGL(assign_cls_label_kernel, grid, dim3(BLOCK), smem, stream,
                       anchorss, gt_bboxess, gt_counts, use_anchor, out, N, A);
}